// Round 14
// baseline (81.886 us; speedup 1.0000x reference)
//
#include <hip/hip_runtime.h>

// Tropical (max-times) matmul: out[i,k] = max_j sigmoid(A[j,k]) * x[i,j]
// x: [2048, 256] f32   A: [256, 512] f32   out: [2048, 512] f32
//
// Round 14: OBSERVABILITY ROUND. R13 (best, 21.7us) implies main ~13us vs
// a 5us model — 2.5x unexplained, and our kernels never enter rocprof's
// top-5 (harness 39us poison-fills occupy it). This round amplifies the
// R13 main kernel body 8x IN-KERNEL (deterministic/idempotent: re-stages
// the same W, recomputes the same acc, rewrites the same out) so the main
// kernel tops the counter table and we finally read VALUBusy / Occupancy /
// LDS_BANK_CONFLICT / FETCH for the real hot structure.
// Discriminating prediction: latency-bound -> dur~104us, VALUBusy 25-35%;
// VALU-bound -> VALUBusy>80%; conflicts -> SQ_LDS_BANK_CONFLICT >> 0.

typedef _Float16 h1;
typedef __attribute__((ext_vector_type(2))) _Float16 h2v;
typedef __attribute__((ext_vector_type(4))) float f4;
typedef __attribute__((ext_vector_type(4))) unsigned int u4;
typedef __attribute__((ext_vector_type(8))) unsigned int u8;

constexpr int JD = 256;
constexpr int KD = 512;

__device__ __forceinline__ float sigmoidf_fast(float a) {
    return 1.0f / (1.0f + __expf(-a));
}

__device__ __forceinline__ h2v asH2(unsigned int u) {
    union { unsigned int x; h2v h; } c; c.x = u; return c.h;
}

// Wq[p4*512 + k] (u4, 16B): q-th h2v = (sig A[8p4+2q][k], sig A[8p4+2q+1][k])
// xp[row*32 + g] (u4): 4 pairs (8 j) of row, fp16.
__global__ __launch_bounds__(256) void prepack(const float* __restrict__ x,
                                               const float* __restrict__ A,
                                               u4* __restrict__ Wq,
                                               u4* __restrict__ xp4) {
    const int b = (int)blockIdx.x;
    if (b < 64) {   // W part
        const int t  = b * 256 + (int)threadIdx.x;
        const int p4 = t >> 9;
        const int k  = t & 511;
        union { u4 v; h2v h[4]; } u;
        #pragma unroll
        for (int q = 0; q < 4; ++q) {
            const float a0 = A[(8 * p4 + 2 * q) * KD + k];
            const float a1 = A[(8 * p4 + 2 * q + 1) * KD + k];
            u.h[q] = h2v{(h1)sigmoidf_fast(a0), (h1)sigmoidf_fast(a1)};
        }
        Wq[p4 * 512 + k] = u.v;
    } else {        // x part
        const int g = (b - 64) * 256 + (int)threadIdx.x;
        const f4 x0 = *(const f4*)&x[g * 8];
        const f4 x1 = *(const f4*)&x[g * 8 + 4];
        union { u4 v; h2v h[4]; } u;
        u.h[0] = h2v{(h1)x0.x, (h1)x0.y};
        u.h[1] = h2v{(h1)x0.z, (h1)x0.w};
        u.h[2] = h2v{(h1)x1.x, (h1)x1.y};
        u.h[3] = h2v{(h1)x1.z, (h1)x1.w};
        xp4[g] = u.v;
    }
}

__global__ __launch_bounds__(256) void tropical_main(
        const unsigned int* __restrict__ xp,
        const u4* __restrict__ Wq,
        float* __restrict__ out) {
    __shared__ u4 Wl[32 * 64];   // [p4][k_local], 32KB

    const int t    = (int)threadIdx.x;
    const int lane = t & 63;
    const int wv   = __builtin_amdgcn_readfirstlane(t >> 6);
    const int kg   = (int)blockIdx.x & 7;
    const int rg   = (int)blockIdx.x >> 3;
    const int k0   = kg * 64;
    const int r0   = rg * 16 + wv * 4;

    // ======== 8x amplification of the ENTIRE R13 body ========
    #pragma unroll 1
    for (int rep = 0; rep < 8; ++rep) {

        // ---- stage W slab (idempotent: same values every rep) ----
        #pragma unroll
        for (int i = 0; i < 8; ++i) {
            const int p4 = wv * 8 + i;
            Wl[p4 * 64 + lane] = Wq[p4 * 512 + k0 + lane];
        }
        __syncthreads();

        const unsigned int* xr = xp + r0 * 128;

        h2v acc[4];
        #pragma unroll
        for (int r = 0; r < 4; ++r)
            acc[r] = h2v{(h1)(-65504.0f), (h1)(-65504.0f)};

        #pragma unroll 2
        for (int c = 0; c < 16; ++c) {
            u8 X[4];
            #pragma unroll
            for (int r = 0; r < 4; ++r)
                X[r] = *(const u8*)(xr + r * 128 + c * 8);

            union { u4 v; h2v h[4]; } w0, w1;
            w0.v = Wl[(2 * c + 0) * 64 + lane];
            w1.v = Wl[(2 * c + 1) * 64 + lane];

            #pragma unroll
            for (int r = 0; r < 4; ++r) {
                #pragma unroll
                for (int q = 0; q < 4; ++q) {
                    acc[r] = __builtin_elementwise_max(acc[r],
                                                       asH2(X[r][q]) * w0.h[q]);
                    acc[r] = __builtin_elementwise_max(acc[r],
                                                       asH2(X[r][4 + q]) * w1.h[q]);
                }
            }
        }

        const int k = k0 + lane;
        #pragma unroll
        for (int r = 0; r < 4; ++r)
            out[(r0 + r) * KD + k] = fmaxf((float)acc[r][0], (float)acc[r][1]);

        __syncthreads();   // keep reps cleanly separated (same data rewritten)
    }
}

extern "C" void kernel_launch(void* const* d_in, const int* in_sizes, int n_in,
                              void* d_out, int out_size, void* d_ws, size_t ws_size,
                              hipStream_t stream) {
    const float* x = (const float*)d_in[0];
    const float* A = (const float*)d_in[1];
    float* out = (float*)d_out;

    u4* Wq  = (u4*)d_ws;
    u4* xp4 = (u4*)((char*)d_ws + 256 * 1024);

    hipLaunchKernelGGL(prepack, dim3(320), dim3(256), 0, stream, x, A, Wq, xp4);
    hipLaunchKernelGGL(tropical_main, dim3(1024), dim3(256), 0, stream,
                       (const unsigned int*)xp4, Wq, out);
}

// Round 15
// 27.727 us; speedup vs baseline: 2.9533x; 2.9533x over previous
//
#include <hip/hip_runtime.h>

// Tropical (max-times) matmul: out[i,k] = max_j sigmoid(A[j,k]) * x[i,j]
// x: [2048, 256] f32   A: [256, 512] f32   out: [2048, 512] f32
//
// Round 15: single fused dispatch + asm-guaranteed packed fp16 math.
// R14 counters: VALUBusy ~70% (VALU-bound) but 2x the modeled pk count;
// plus ~5-8us of prepack-dispatch+gap fixed cost. This round:
//  - ONE kernel. Phase 0: each block packs its rowgroup's x (16x256 f32
//    -> fp16 pairs) into a rowgroup-shared d_ws slab (blocks sharing a
//    rowgroup write byte-identical data; each block reads only after
//    vmcnt(0)+barrier of its own complete writes -> race-safe).
//  - Phase 1: W sigmoid fused into LDS staging ([p4][k] 16B cells, 32KB).
//  - Phase 2: X via explicit s_load_dwordx8 asm (compiler would refuse
//    s_load after in-kernel stores), W via ds_read_b128 asm; ONE
//    lgkmcnt(0) per chunk, operand-tied (rule #18); double-buffered.
//    Math: v_pk_mul_f16 (SGPR x-operand) + v_pk_max_f16 via asm.
//  - grid 1024 (4 blocks/CU, 16 waves/CU), VALU floor ~3.4us.

typedef _Float16 h1;
typedef __attribute__((ext_vector_type(2))) _Float16 h2v;
typedef __attribute__((ext_vector_type(4))) float f4;
typedef __attribute__((ext_vector_type(4))) unsigned int u4;
typedef __attribute__((ext_vector_type(8))) unsigned int u8;

constexpr int JD = 256;
constexpr int KD = 512;

__device__ __forceinline__ float sigmoidf_fast(float a) {
    return 1.0f / (1.0f + __expf(-a));
}

__global__ __launch_bounds__(256) void tropical_one(
        const float* __restrict__ x,
        const float* __restrict__ A,
        float* __restrict__ out,
        unsigned int* ws) {              // no restrict: written then read
    __shared__ u4 Wl[32 * 64];           // [p4][k_local] 16B cells = 32 KB

    const int t    = (int)threadIdx.x;
    const int lane = t & 63;
    const int wv   = __builtin_amdgcn_readfirstlane(t >> 6);   // 0..3
    const int kg   = (int)blockIdx.x & 7;      // 8 k-groups of 64
    const int rg   = (int)blockIdx.x >> 3;     // 128 row-groups of 16
    const int k0   = kg * 64;
    const int i0   = rg * 16;

    // ---- phase 0: pack my rowgroup's x into the shared ws slab ----
    {
        const int row = t >> 4;                 // 0..15
        const int cb  = (t & 15) * 16;          // float col base
        const float* xs = x + (i0 + row) * JD + cb;
        f4 v0 = ((const f4*)xs)[0];
        f4 v1 = ((const f4*)xs)[1];
        f4 v2 = ((const f4*)xs)[2];
        f4 v3 = ((const f4*)xs)[3];
        union { u4 v; h2v h[4]; } a, b;
        a.h[0] = h2v{(h1)v0.x, (h1)v0.y};
        a.h[1] = h2v{(h1)v0.z, (h1)v0.w};
        a.h[2] = h2v{(h1)v1.x, (h1)v1.y};
        a.h[3] = h2v{(h1)v1.z, (h1)v1.w};
        b.h[0] = h2v{(h1)v2.x, (h1)v2.y};
        b.h[1] = h2v{(h1)v2.z, (h1)v2.w};
        b.h[2] = h2v{(h1)v3.x, (h1)v3.y};
        b.h[3] = h2v{(h1)v3.z, (h1)v3.w};
        unsigned int* dst = ws + rg * 2048 + row * 128 + (t & 15) * 8;
        *(u4*)dst       = a.v;
        *(u4*)(dst + 4) = b.v;
    }
    // my slab writes must reach L2 before my s_loads
    asm volatile("s_waitcnt vmcnt(0)" ::: "memory");

    // ---- phase 1: W staging with fused sigmoid ----
    {
        const int grp = t >> 6;                 // 0..3
        const float* Ak = A + k0 + lane;
        #pragma unroll 2
        for (int pass = 0; pass < 8; ++pass) {
            const int p4 = grp * 8 + pass;      // 0..31
            union { u4 v; h2v h[4]; } u;
            #pragma unroll
            for (int q = 0; q < 4; ++q) {
                const float a0 = Ak[(8 * p4 + 2 * q) * KD];
                const float a1 = Ak[(8 * p4 + 2 * q + 1) * KD];
                u.h[q] = h2v{(h1)sigmoidf_fast(a0), (h1)sigmoidf_fast(a1)};
            }
            Wl[p4 * 64 + lane] = u.v;
        }
    }
    __syncthreads();

    // ---- phase 2: double-buffered asm pipeline ----
    const unsigned int* xrow = ws + rg * 2048 + wv * 4 * 128;   // uniform
    const unsigned int voffb =
        (unsigned int)(unsigned long long)(&Wl[0]) + (unsigned int)lane * 16u;

    unsigned int acc[4] = {0xFBFFFBFFu, 0xFBFFFBFFu, 0xFBFFFBFFu, 0xFBFFFBFFu};

    u8 X[2][4];
    u4 W[2][2];

    auto issue = [&](int buf, int c) {
        const unsigned int* p = xrow + c * 8;
        asm volatile("s_load_dwordx8 %0, %1, 0x0" : "=s"(X[buf][0]) : "s"(p));
        asm volatile("s_load_dwordx8 %0, %1, 0x0" : "=s"(X[buf][1]) : "s"(p + 128));
        asm volatile("s_load_dwordx8 %0, %1, 0x0" : "=s"(X[buf][2]) : "s"(p + 256));
        asm volatile("s_load_dwordx8 %0, %1, 0x0" : "=s"(X[buf][3]) : "s"(p + 384));
        const unsigned int vo = voffb + (unsigned int)c * 2048u;
        asm volatile("ds_read_b128 %0, %1" : "=v"(W[buf][0]) : "v"(vo));
        asm volatile("ds_read_b128 %0, %1" : "=v"(W[buf][1]) : "v"(vo + 1024u));
    };
    auto wait = [&](int buf) {
        asm volatile("s_waitcnt lgkmcnt(0)"
                     : "+s"(X[buf][0]), "+s"(X[buf][1]),
                       "+s"(X[buf][2]), "+s"(X[buf][3]),
                       "+v"(W[buf][0]), "+v"(W[buf][1]));
    };
    auto compute = [&](int buf) {
        union { u4 v; unsigned int d[4]; } w0, w1;
        w0.v = W[buf][0];
        w1.v = W[buf][1];
        #pragma unroll
        for (int r = 0; r < 4; ++r) {
            #pragma unroll
            for (int q = 0; q < 4; ++q) {
                unsigned int p0, p1;
                asm("v_pk_mul_f16 %0, %1, %2"
                    : "=v"(p0) : "s"(X[buf][r][q]), "v"(w0.d[q]));
                asm("v_pk_max_f16 %0, %1, %0" : "+v"(acc[r]) : "v"(p0));
                asm("v_pk_mul_f16 %0, %1, %2"
                    : "=v"(p1) : "s"(X[buf][r][4 + q]), "v"(w1.d[q]));
                asm("v_pk_max_f16 %0, %1, %0" : "+v"(acc[r]) : "v"(p1));
            }
        }
    };

    issue(0, 0);
    wait(0);
    #pragma unroll
    for (int c = 0; c < 16; ++c) {
        const int cur = c & 1, nxt = cur ^ 1;
        if (c + 1 < 16) issue(nxt, c + 1);
        compute(cur);
        if (c + 1 < 16) wait(nxt);
    }

    // ---- epilogue: fold pair halves, coalesced dword stores ----
    #pragma unroll
    for (int r = 0; r < 4; ++r) {
        union { unsigned int u; h2v h; } cv;
        cv.u = acc[r];
        out[(i0 + wv * 4 + r) * KD + k0 + lane] =
            fmaxf((float)cv.h[0], (float)cv.h[1]);
    }
}

extern "C" void kernel_launch(void* const* d_in, const int* in_sizes, int n_in,
                              void* d_out, int out_size, void* d_ws, size_t ws_size,
                              hipStream_t stream) {
    const float* x = (const float*)d_in[0];
    const float* A = (const float*)d_in[1];
    float* out = (float*)d_out;
    unsigned int* ws = (unsigned int*)d_ws;    // 1 MB (proven available)

    // 1024 blocks = (128 rowgroups) x (8 k-groups); 4 blocks/CU
    hipLaunchKernelGGL(tropical_one, dim3(1024), dim3(256), 0, stream,
                       x, A, out, ws);
}

// Round 16
// 27.660 us; speedup vs baseline: 2.9605x; 1.0024x over previous
//
#include <hip/hip_runtime.h>

// Tropical (max-times) matmul: out[i,k] = max_j sigmoid(A[j,k]) * x[i,j]
// x: [2048, 256] f32   A: [256, 512] f32   out: [2048, 512] f32
//
// Round 16: single dispatch, R13's proven main-loop style (plain C++,
// compiler-scheduled SGPR ping-pong), fusion done by changing WHAT is
// loaded, not HOW:
//  - x: f32 s_load_dwordx8 straight from the input (no prepack, no ws
//    writes -> no vmcnt hazard, scalarization stays legal). JC=8 ->
//    32 SGPRs/chunk, ping-pong 64 (R13-proven budget).
//  - W: staged per block with fused sigmoid into the R13 conflict-free
//    [cell][k] 16B LDS layout (32KB). 64 sigmoids/thread (~R10-proven).
//  - math: f32 (v_mul_f32 s,v + v_max3_f32), W cvt fp16->f32 8/chunk
//    shared across rows. acc f32 -> absmax ~3e-3.
//  - grid 1024 (4 blocks/CU, 16 waves/CU).

typedef _Float16 h1;
typedef __attribute__((ext_vector_type(2))) _Float16 h2v;
typedef __attribute__((ext_vector_type(4))) float f4;
typedef __attribute__((ext_vector_type(8))) float f8;
typedef __attribute__((ext_vector_type(4))) unsigned int u4;

constexpr int JD = 256;
constexpr int KD = 512;

__device__ __forceinline__ float sigmoidf_fast(float a) {
    return 1.0f / (1.0f + __expf(-a));
}

__global__ __launch_bounds__(256) void tropical_one(
        const float* __restrict__ x,
        const float* __restrict__ A,
        float* __restrict__ out) {
    __shared__ u4 Wl[32 * 64];   // [cell c][k_local]: 8 j (4 fp16 pairs) per cell

    const int t    = (int)threadIdx.x;
    const int lane = t & 63;
    const int wv   = __builtin_amdgcn_readfirstlane(t >> 6);   // 0..3
    const int kg   = (int)blockIdx.x & 7;      // 8 k-groups of 64
    const int rg   = (int)blockIdx.x >> 3;     // 128 row-groups of 16
    const int k0   = kg * 64;
    const int i0   = rg * 16;

    // ---- stage W with fused sigmoid: cell c, k=lane covers j=8c..8c+7 ----
    {
        const float* Ak = A + k0 + lane;       // lane-coalesced columns
        const int c0 = (t >> 6) * 8;           // this wave's 8 cells
        #pragma unroll 2
        for (int cc = 0; cc < 8; ++cc) {
            const int c = c0 + cc;
            union { u4 v; h2v h[4]; } u;
            #pragma unroll
            for (int q = 0; q < 4; ++q) {
                const float a0 = Ak[(8 * c + 2 * q) * KD];
                const float a1 = Ak[(8 * c + 2 * q + 1) * KD];
                u.h[q] = h2v{(h1)sigmoidf_fast(a0), (h1)sigmoidf_fast(a1)};
            }
            Wl[c * 64 + lane] = u.v;           // 16B-stride, conflict-free
        }
    }
    __syncthreads();

    const float* xr = x + (i0 + wv * 4) * JD;  // uniform base (wave's 4 rows)

    float acc[4];
    #pragma unroll
    for (int r = 0; r < 4; ++r) acc[r] = -__builtin_inff();

    // ---- main loop: 32 chunks of 8 j; SGPR x ping-pong, LDS W + cvt ----
    #pragma unroll 2
    for (int c = 0; c < 32; ++c) {
        f8 X[4];                               // 4 rows x 8 f32 (SGPRs)
        #pragma unroll
        for (int r = 0; r < 4; ++r)
            X[r] = *(const f8*)(xr + r * JD + c * 8);

        union { u4 v; h2v h[4]; } w;
        w.v = Wl[c * 64 + lane];               // 1 conflict-free b128

        float wf[8];                           // cvt shared across 4 rows
        #pragma unroll
        for (int q = 0; q < 4; ++q) {
            wf[2 * q]     = (float)w.h[q][0];
            wf[2 * q + 1] = (float)w.h[q][1];
        }

        #pragma unroll
        for (int r = 0; r < 4; ++r) {
            #pragma unroll
            for (int q = 0; q < 4; ++q) {
                // fmaxf(fmaxf(p0,p1),acc) -> v_max3_f32
                acc[r] = fmaxf(fmaxf(X[r][2 * q] * wf[2 * q],
                                     X[r][2 * q + 1] * wf[2 * q + 1]),
                               acc[r]);
            }
        }
    }

    // ---- epilogue: coalesced dword stores (acc already f32) ----
    #pragma unroll
    for (int r = 0; r < 4; ++r)
        out[(i0 + wv * 4 + r) * KD + k0 + lane] = acc[r];
}

extern "C" void kernel_launch(void* const* d_in, const int* in_sizes, int n_in,
                              void* d_out, int out_size, void* d_ws, size_t ws_size,
                              hipStream_t stream) {
    const float* x = (const float*)d_in[0];
    const float* A = (const float*)d_in[1];
    float* out = (float*)d_out;

    // 1024 blocks = (128 rowgroups) x (8 k-groups); 4 blocks/CU, 16 waves/CU
    hipLaunchKernelGGL(tropical_one, dim3(1024), dim3(256), 0, stream,
                       x, A, out);
}

// Round 17
// 22.435 us; speedup vs baseline: 3.6499x; 1.2329x over previous
//
#include <hip/hip_runtime.h>

// Tropical (max-times) matmul: out[i,k] = max_j sigmoid(A[j,k]) * x[i,j]
// x: [2048, 256] f32   A: [256, 512] f32   out: [2048, 512] f32
//
// Round 17 = R13 (best, 21.7us) with ONE change: the inner math is inline
// asm v_pk_mul_f16 (explicit "s" constraint on the x operand — legal: one
// SGPR read per VALU instr) + v_pk_max_f16. R14's counters showed VALU
// issue ~2x the ideal pk count; suspected __builtin_elementwise_max
// splitting into 2x v_max_f16 and/or s->v movs before the muls. All loads
// stay plain C++ (compiler scheduling + waitcnt insertion preserved; asm
// consumes register defs, so the compiler's lgkmcnt still guards them).

typedef _Float16 h1;
typedef __attribute__((ext_vector_type(2))) _Float16 h2v;
typedef __attribute__((ext_vector_type(4))) float f4;
typedef __attribute__((ext_vector_type(4))) unsigned int u4;
typedef __attribute__((ext_vector_type(8))) unsigned int u8;

constexpr int JD = 256;
constexpr int KD = 512;

__device__ __forceinline__ float sigmoidf_fast(float a) {
    return 1.0f / (1.0f + __expf(-a));
}

// Wq[p4*512 + k] (u4, 16B): q-th h2v = (sig A[8p4+2q][k], sig A[8p4+2q+1][k])
// xp[row*32 + g] (u4): 4 pairs (8 j) of row, fp16.
__global__ __launch_bounds__(256) void prepack(const float* __restrict__ x,
                                               const float* __restrict__ A,
                                               u4* __restrict__ Wq,
                                               u4* __restrict__ xp4) {
    const int b = (int)blockIdx.x;
    if (b < 64) {   // W part: 16384 threads, one per (p4, k)
        const int t  = b * 256 + (int)threadIdx.x;
        const int p4 = t >> 9;
        const int k  = t & 511;
        union { u4 v; h2v h[4]; } u;
        #pragma unroll
        for (int q = 0; q < 4; ++q) {
            const float a0 = A[(8 * p4 + 2 * q) * KD + k];
            const float a1 = A[(8 * p4 + 2 * q + 1) * KD + k];
            u.h[q] = h2v{(h1)sigmoidf_fast(a0), (h1)sigmoidf_fast(a1)};
        }
        Wq[p4 * 512 + k] = u.v;
    } else {        // x part: 65536 threads, 8 floats -> 1 u4 each
        const int g = (b - 64) * 256 + (int)threadIdx.x;
        const f4 x0 = *(const f4*)&x[g * 8];
        const f4 x1 = *(const f4*)&x[g * 8 + 4];
        union { u4 v; h2v h[4]; } u;
        u.h[0] = h2v{(h1)x0.x, (h1)x0.y};
        u.h[1] = h2v{(h1)x0.z, (h1)x0.w};
        u.h[2] = h2v{(h1)x1.x, (h1)x1.y};
        u.h[3] = h2v{(h1)x1.z, (h1)x1.w};
        xp4[g] = u.v;
    }
}

__global__ __launch_bounds__(256) void tropical_main(
        const unsigned int* __restrict__ xp,   // dword view of xp4
        const u4* __restrict__ Wq,
        float* __restrict__ out) {
    __shared__ u4 Wl[32 * 64];   // [p4][k_local], 16B cells = 32KB

    const int t    = (int)threadIdx.x;
    const int lane = t & 63;
    const int wv   = __builtin_amdgcn_readfirstlane(t >> 6);   // 0..3
    const int kg   = (int)blockIdx.x & 7;      // 8 k-groups of 64
    const int rg   = (int)blockIdx.x >> 3;     // 128 row-groups of 16
    const int k0   = kg * 64;
    const int r0   = rg * 16 + wv * 4;         // this wave's 4 rows

    // ---- stage W slab (32 p4-rows x 64 k): coalesced 1KB global reads,
    //      16B-stride LDS writes (conflict-free, R14-verified 0 conflicts)
    #pragma unroll
    for (int i = 0; i < 8; ++i) {
        const int p4 = wv * 8 + i;
        Wl[p4 * 64 + lane] = Wq[p4 * 512 + k0 + lane];
    }
    __syncthreads();

    const unsigned int* xr = xp + r0 * 128;    // 128 dwords per row (uniform)

    unsigned int acc[4] = {0xFBFFFBFFu, 0xFBFFFBFFu, 0xFBFFFBFFu, 0xFBFFFBFFu};

    // ---- main loop: 16 chunks of 8 pairs (16 j) ----
    #pragma unroll 2
    for (int c = 0; c < 16; ++c) {
        // x: 4 rows x 32B, uniform addresses -> s_load_dwordx8 each
        u8 X[4];
        #pragma unroll
        for (int r = 0; r < 4; ++r)
            X[r] = *(const u8*)(xr + r * 128 + c * 8);

        // W: 2 quad-pairs for this chunk, per-lane column, b128 16B-stride
        union { u4 v; unsigned int d[4]; } w0, w1;
        w0.v = Wl[(2 * c + 0) * 64 + lane];
        w1.v = Wl[(2 * c + 1) * 64 + lane];

        #pragma unroll
        for (int r = 0; r < 4; ++r) {
            #pragma unroll
            for (int q = 0; q < 4; ++q) {
                unsigned int p0, p1;
                // v_pk_mul_f16 vdst, sgpr, vgpr  (1 SGPR read: legal)
                asm("v_pk_mul_f16 %0, %1, %2"
                    : "=v"(p0) : "s"(X[r][q]), "v"(w0.d[q]));
                asm("v_pk_max_f16 %0, %1, %0" : "+v"(acc[r]) : "v"(p0));
                asm("v_pk_mul_f16 %0, %1, %2"
                    : "=v"(p1) : "s"(X[r][4 + q]), "v"(w1.d[q]));
                asm("v_pk_max_f16 %0, %1, %0" : "+v"(acc[r]) : "v"(p1));
            }
        }
    }

    // ---- epilogue: fold pair halves, coalesced dword stores ----
    const int k = k0 + lane;
    #pragma unroll
    for (int r = 0; r < 4; ++r) {
        union { unsigned int u; h2v h; } cv;
        cv.u = acc[r];
        out[(r0 + r) * KD + k] = fmaxf((float)cv.h[0], (float)cv.h[1]);
    }
}

extern "C" void kernel_launch(void* const* d_in, const int* in_sizes, int n_in,
                              void* d_out, int out_size, void* d_ws, size_t ws_size,
                              hipStream_t stream) {
    const float* x = (const float*)d_in[0];
    const float* A = (const float*)d_in[1];
    float* out = (float*)d_out;

    u4* Wq  = (u4*)d_ws;                                 // 256 KB
    u4* xp4 = (u4*)((char*)d_ws + 256 * 1024);           // 1 MB

    hipLaunchKernelGGL(prepack, dim3(320), dim3(256), 0, stream, x, A, Wq, xp4);

    // 1024 blocks = (128 row-groups) x (8 k-groups); 4 blocks/CU, 16 waves/CU
    hipLaunchKernelGGL(tropical_main, dim3(1024), dim3(256), 0, stream,
                       (const unsigned int*)xp4, Wq, out);
}

// Round 18
// 22.102 us; speedup vs baseline: 3.7050x; 1.0151x over previous
//
#include <hip/hip_runtime.h>

// Tropical (max-times) matmul: out[i,k] = max_j sigmoid(A[j,k]) * x[i,j]
// x: [2048, 256] f32   A: [256, 512] f32   out: [2048, 512] f32
//
// Round 18 = R13 (best, 21.7us) with ONE change: main-loop chunk JC 16->8
// with #pragma unroll 4. Rationale: s_loads retire lgkmcnt OUT OF ORDER,
// so every chunk boundary is a full lgkmcnt(0) drain; R13's unroll-2 gave
// only ~1 chunk (~128cyc) of issue-ahead vs 200-300cyc L2 latency -> per-
// chunk bubble (R14: VALUBusy 70%, main 10.3us). JC=8 chunks are 16 SGPRs
// each, so unroll-4 lets the compiler keep 3-4 chunks of X in flight
// (48-64 SGPRs, within budget) -> loads issue 192-256cyc ahead of their
// drain. Math/prepack/layout byte-identical to R13.

typedef _Float16 h1;
typedef __attribute__((ext_vector_type(2))) _Float16 h2v;
typedef __attribute__((ext_vector_type(4))) float f4;
typedef __attribute__((ext_vector_type(4))) unsigned int u4;

constexpr int JD = 256;
constexpr int KD = 512;

__device__ __forceinline__ float sigmoidf_fast(float a) {
    return 1.0f / (1.0f + __expf(-a));
}

__device__ __forceinline__ h2v asH2(unsigned int u) {
    union { unsigned int x; h2v h; } c; c.x = u; return c.h;
}

// Wq[p4*512 + k] (u4, 16B): q-th h2v = (sig A[8p4+2q][k], sig A[8p4+2q+1][k])
// xp[row*32 + g] (u4): 4 pairs (8 j) of row, fp16.
__global__ __launch_bounds__(256) void prepack(const float* __restrict__ x,
                                               const float* __restrict__ A,
                                               u4* __restrict__ Wq,
                                               u4* __restrict__ xp4) {
    const int b = (int)blockIdx.x;
    if (b < 64) {   // W part: 16384 threads, one per (p4, k)
        const int t  = b * 256 + (int)threadIdx.x;
        const int p4 = t >> 9;
        const int k  = t & 511;
        union { u4 v; h2v h[4]; } u;
        #pragma unroll
        for (int q = 0; q < 4; ++q) {
            const float a0 = A[(8 * p4 + 2 * q) * KD + k];
            const float a1 = A[(8 * p4 + 2 * q + 1) * KD + k];
            u.h[q] = h2v{(h1)sigmoidf_fast(a0), (h1)sigmoidf_fast(a1)};
        }
        Wq[p4 * 512 + k] = u.v;
    } else {        // x part: 65536 threads, 8 floats -> 1 u4 each
        const int g = (b - 64) * 256 + (int)threadIdx.x;
        const f4 x0 = *(const f4*)&x[g * 8];
        const f4 x1 = *(const f4*)&x[g * 8 + 4];
        union { u4 v; h2v h[4]; } u;
        u.h[0] = h2v{(h1)x0.x, (h1)x0.y};
        u.h[1] = h2v{(h1)x0.z, (h1)x0.w};
        u.h[2] = h2v{(h1)x1.x, (h1)x1.y};
        u.h[3] = h2v{(h1)x1.z, (h1)x1.w};
        xp4[g] = u.v;
    }
}

__global__ __launch_bounds__(256) void tropical_main(
        const unsigned int* __restrict__ xp,   // dword view of xp4
        const u4* __restrict__ Wq,
        float* __restrict__ out) {
    __shared__ u4 Wl[32 * 64];   // [p4][k_local], 16B cells = 32KB

    const int t    = (int)threadIdx.x;
    const int lane = t & 63;
    const int wv   = __builtin_amdgcn_readfirstlane(t >> 6);   // 0..3
    const int kg   = (int)blockIdx.x & 7;      // 8 k-groups of 64
    const int rg   = (int)blockIdx.x >> 3;     // 128 row-groups of 16
    const int k0   = kg * 64;
    const int r0   = rg * 16 + wv * 4;         // this wave's 4 rows

    // ---- stage W slab (32 p4-rows x 64 k): coalesced 1KB global reads,
    //      16B-stride LDS writes (R14-verified: 0 bank conflicts)
    #pragma unroll
    for (int i = 0; i < 8; ++i) {
        const int p4 = wv * 8 + i;
        Wl[p4 * 64 + lane] = Wq[p4 * 512 + k0 + lane];
    }
    __syncthreads();

    const unsigned int* xr = xp + r0 * 128;    // 128 dwords per row (uniform)

    h2v acc[4];
    #pragma unroll
    for (int r = 0; r < 4; ++r)
        acc[r] = h2v{(h1)(-65504.0f), (h1)(-65504.0f)};

    // ---- main loop: 32 chunks of 4 pairs (8 j); deep SMEM pipeline ----
    #pragma unroll 4
    for (int c = 0; c < 32; ++c) {
        // x: 4 rows x 16B, uniform addresses -> s_load_dwordx4 each
        u4 X[4];
        #pragma unroll
        for (int r = 0; r < 4; ++r)
            X[r] = *(const u4*)(xr + r * 128 + c * 4);

        // W: 1 quad-pair cell, per-lane column, conflict-free b128
        union { u4 v; h2v h[4]; } w;
        w.v = Wl[c * 64 + lane];

        #pragma unroll
        for (int r = 0; r < 4; ++r) {
            #pragma unroll
            for (int q = 0; q < 4; ++q)
                acc[r] = __builtin_elementwise_max(acc[r],
                                                   asH2(X[r][q]) * w.h[q]);
        }
    }

    // ---- epilogue: fold pair halves, coalesced dword stores ----
    const int k = k0 + lane;
    #pragma unroll
    for (int r = 0; r < 4; ++r)
        out[(r0 + r) * KD + k] = fmaxf((float)acc[r][0], (float)acc[r][1]);
}

extern "C" void kernel_launch(void* const* d_in, const int* in_sizes, int n_in,
                              void* d_out, int out_size, void* d_ws, size_t ws_size,
                              hipStream_t stream) {
    const float* x = (const float*)d_in[0];
    const float* A = (const float*)d_in[1];
    float* out = (float*)d_out;

    u4* Wq  = (u4*)d_ws;                                 // 256 KB
    u4* xp4 = (u4*)((char*)d_ws + 256 * 1024);           // 1 MB

    hipLaunchKernelGGL(prepack, dim3(320), dim3(256), 0, stream, x, A, Wq, xp4);

    // 1024 blocks = (128 row-groups) x (8 k-groups); 4 blocks/CU, 16 waves/CU
    hipLaunchKernelGGL(tropical_main, dim3(1024), dim3(256), 0, stream,
                       (const unsigned int*)xp4, Wq, out);
}

// Round 19
// 22.036 us; speedup vs baseline: 3.7160x; 1.0030x over previous
//
#include <hip/hip_runtime.h>

// Tropical (max-times) matmul: out[i,k] = max_j sigmoid(A[j,k]) * x[i,j]
// x: [2048, 256] f32   A: [256, 512] f32   out: [2048, 512] f32
//
// Round 19 = R13 with ONE change: occupancy. R14 measured Occupancy ~29%
// (~9.3 waves/CU effective, not the nominal 16) — which also explains the
// "2x VALU" residue without clock throttle. This round: 512-thread blocks
// (8 waves) x TI=2 rows/wave, grid 1024; one 32KB W slab per block ->
// 4 blocks/CU = 32 waves/CU (hardware max), smoother tail. At full
// occupancy VALU ~16.8k cyc/CU still > LDS ~12.3k (b128 pipe hidden).
// Prepack, layouts, JC=16 loop, math: byte-identical to R13.

typedef _Float16 h1;
typedef __attribute__((ext_vector_type(2))) _Float16 h2v;
typedef __attribute__((ext_vector_type(4))) float f4;
typedef __attribute__((ext_vector_type(4))) unsigned int u4;
typedef __attribute__((ext_vector_type(8))) unsigned int u8;

constexpr int JD = 256;
constexpr int KD = 512;

__device__ __forceinline__ float sigmoidf_fast(float a) {
    return 1.0f / (1.0f + __expf(-a));
}

__device__ __forceinline__ h2v asH2(unsigned int u) {
    union { unsigned int x; h2v h; } c; c.x = u; return c.h;
}

// Wq[p4*512 + k] (u4, 16B): q-th h2v = (sig A[8p4+2q][k], sig A[8p4+2q+1][k])
// xp[row*32 + g] (u4): 4 pairs (8 j) of row, fp16.
__global__ __launch_bounds__(256) void prepack(const float* __restrict__ x,
                                               const float* __restrict__ A,
                                               u4* __restrict__ Wq,
                                               u4* __restrict__ xp4) {
    const int b = (int)blockIdx.x;
    if (b < 64) {   // W part: 16384 threads, one per (p4, k)
        const int t  = b * 256 + (int)threadIdx.x;
        const int p4 = t >> 9;
        const int k  = t & 511;
        union { u4 v; h2v h[4]; } u;
        #pragma unroll
        for (int q = 0; q < 4; ++q) {
            const float a0 = A[(8 * p4 + 2 * q) * KD + k];
            const float a1 = A[(8 * p4 + 2 * q + 1) * KD + k];
            u.h[q] = h2v{(h1)sigmoidf_fast(a0), (h1)sigmoidf_fast(a1)};
        }
        Wq[p4 * 512 + k] = u.v;
    } else {        // x part: 65536 threads, 8 floats -> 1 u4 each
        const int g = (b - 64) * 256 + (int)threadIdx.x;
        const f4 x0 = *(const f4*)&x[g * 8];
        const f4 x1 = *(const f4*)&x[g * 8 + 4];
        union { u4 v; h2v h[4]; } u;
        u.h[0] = h2v{(h1)x0.x, (h1)x0.y};
        u.h[1] = h2v{(h1)x0.z, (h1)x0.w};
        u.h[2] = h2v{(h1)x1.x, (h1)x1.y};
        u.h[3] = h2v{(h1)x1.z, (h1)x1.w};
        xp4[g] = u.v;
    }
}

__global__ __launch_bounds__(512) void tropical_main(
        const unsigned int* __restrict__ xp,   // dword view of xp4
        const u4* __restrict__ Wq,
        float* __restrict__ out) {
    __shared__ u4 Wl[32 * 64];   // [p4][k_local], 16B cells = 32KB

    const int t    = (int)threadIdx.x;
    const int lane = t & 63;
    const int wv   = __builtin_amdgcn_readfirstlane(t >> 6);   // 0..7
    const int kg   = (int)blockIdx.x & 7;      // 8 k-groups of 64
    const int rg   = (int)blockIdx.x >> 3;     // 128 row-groups of 16
    const int k0   = kg * 64;
    const int r0   = rg * 16 + wv * 2;         // this wave's 2 rows

    // ---- stage W slab (32 p4-rows x 64 k): 4 cells per thread ----
    #pragma unroll
    for (int i = 0; i < 4; ++i) {
        const int p4 = wv * 4 + i;
        Wl[p4 * 64 + lane] = Wq[p4 * 512 + k0 + lane];
    }
    __syncthreads();

    const unsigned int* xr = xp + r0 * 128;    // 128 dwords per row (uniform)

    h2v acc[2];
    acc[0] = h2v{(h1)(-65504.0f), (h1)(-65504.0f)};
    acc[1] = acc[0];

    // ---- main loop: 16 chunks of 8 pairs (16 j) ----
    #pragma unroll 2
    for (int c = 0; c < 16; ++c) {
        // x: 2 rows x 32B, uniform addresses -> s_load_dwordx8 each
        u8 X[2];
        #pragma unroll
        for (int r = 0; r < 2; ++r)
            X[r] = *(const u8*)(xr + r * 128 + c * 8);

        // W: 2 quad-pair cells, per-lane column, conflict-free b128
        union { u4 v; h2v h[4]; } w0, w1;
        w0.v = Wl[(2 * c + 0) * 64 + lane];
        w1.v = Wl[(2 * c + 1) * 64 + lane];

        #pragma unroll
        for (int r = 0; r < 2; ++r) {
            #pragma unroll
            for (int q = 0; q < 4; ++q) {
                acc[r] = __builtin_elementwise_max(acc[r],
                                                   asH2(X[r][q]) * w0.h[q]);
                acc[r] = __builtin_elementwise_max(acc[r],
                                                   asH2(X[r][4 + q]) * w1.h[q]);
            }
        }
    }

    // ---- epilogue: fold pair halves, coalesced dword stores ----
    const int k = k0 + lane;
    #pragma unroll
    for (int r = 0; r < 2; ++r)
        out[(r0 + r) * KD + k] = fmaxf((float)acc[r][0], (float)acc[r][1]);
}

extern "C" void kernel_launch(void* const* d_in, const int* in_sizes, int n_in,
                              void* d_out, int out_size, void* d_ws, size_t ws_size,
                              hipStream_t stream) {
    const float* x = (const float*)d_in[0];
    const float* A = (const float*)d_in[1];
    float* out = (float*)d_out;

    u4* Wq  = (u4*)d_ws;                                 // 256 KB
    u4* xp4 = (u4*)((char*)d_ws + 256 * 1024);           // 1 MB

    hipLaunchKernelGGL(prepack, dim3(320), dim3(256), 0, stream, x, A, Wq, xp4);

    // 1024 blocks = (128 row-groups) x (8 k-groups); 512 thr = 8 waves;
    // 4 blocks/CU = 32 waves/CU (hardware max)
    hipLaunchKernelGGL(tropical_main, dim3(1024), dim3(512), 0, stream,
                       (const unsigned int*)xp4, Wq, out);
}